// Round 12
// baseline (111.759 us; speedup 1.0000x reference)
//
#include <hip/hip_runtime.h>
#include <stdint.h>

typedef __bf16 bf16_t;
typedef bf16_t bf16x8 __attribute__((ext_vector_type(8)));
typedef float f32x4 __attribute__((ext_vector_type(4)));
typedef uint32_t u32x4 __attribute__((ext_vector_type(4)));
typedef uint16_t u16x8 __attribute__((ext_vector_type(8)));

union FragU { u32x4 u; bf16x8 v; u16x8 s; };

__device__ __forceinline__ uint16_t f2bf_rne(float f) {
  uint32_t u = __float_as_uint(f);
  return (uint16_t)((u + 0x7fffu + ((u >> 16) & 1u)) >> 16);
}

// ---------------------------------------------------------------------------
// Kernel 1: pack W (512x52 f32) into MFMA B-fragment layout, single bf16.
// B-frag for mfma_f32_16x16x32_bf16: lane l holds B[k][n], n = nt*16+(l&15),
// k = ks*32 + (l>>4)*8 + j. N padded 52->64. ws: wf[4096] u32x4 (64 KB).
// ---------------------------------------------------------------------------
__global__ __launch_bounds__(256) void pack_w_kernel(
    const float* __restrict__ W, u32x4* __restrict__ wf) {
  int idx = blockIdx.x * 256 + threadIdx.x;
  if (idx >= 4096) return;
  int lane = idx & 63;
  int nt   = (idx >> 6) & 3;
  int ks   = idx >> 8;
  int n  = nt * 16 + (lane & 15);
  int kb = ks * 32 + (lane >> 4) * 8;
  FragU hi;
#pragma unroll
  for (int j = 0; j < 8; ++j) {
    float w = (n < 52) ? W[(kb + j) * 52 + n] : 0.0f;
    hi.s[j] = f2bf_rne(w);
  }
  wf[idx] = hi.u;
}

#define MFMA16(a, b, c) __builtin_amdgcn_mfma_f32_16x16x32_bf16((a), (b), (c), 0, 0, 0)

// ---------------------------------------------------------------------------
// Kernel 2: fused GEMM + bias + softmax(13) + rule mix.
// r11 structure with 64 ROWS PER WAVE (4 M-tiles): B-frag loads amortize
// 2x better (VMEM 4 -> 3 instr/row). Block = 256 rows, 4 waves; barrier-free
// split-wait K-loop: vmcnt(12) [drain stage(ks); B(ks)+stage(ks+1) fly]
// -> ds_read+cvt -> vmcnt(8) [drain B(ks)] -> 16 MFMA -> LOADB(ks+1),
// STAGE(ks+2). LDS union: staging [4][2][8192]=64 KB / logits[256][65] f32.
// 2 blocks/CU (133 KB), 8 waves/CU.
// ---------------------------------------------------------------------------
__global__ __launch_bounds__(256, 2) void raven_main_kernel(
    const float* __restrict__ z, const float* __restrict__ xq,
    const u32x4* __restrict__ wfh,
    const float* __restrict__ bias, float* __restrict__ out) {
  __shared__ __align__(16) unsigned char smem[66560];  // max(65536, 256*65*4)
  __shared__ float lds_bias[52];

  const int tid  = threadIdx.x;
  const int wave = tid >> 6;
  const int lane = tid & 63;
  const int r  = lane & 15;   // A row within 16-tile / C col
  const int kg = lane >> 4;   // k-group (8 contiguous k per lane)

  if (tid < 52) lds_bias[tid] = bias[tid];

  const long long brow = (long long)blockIdx.x * 256;
  const long long wrow = brow + (long long)wave * 64;
  const float* zb = z + wrow * 512;

  unsigned char* stg = smem + wave * 16384;  // [2][8192]

  // staging instr i covers rows i*8+(lane>>3), 8 lanes x 16 B per row;
  // source col pre-swizzled: foff = 4*((lane&7)^rloc)  (HW-verified r6)
  const int rloc = lane >> 3;
  const int foff = 4 * ((lane & 7) ^ rloc);

  f32x4 acc[4][4];
#pragma unroll
  for (int mt = 0; mt < 4; ++mt)
#pragma unroll
    for (int nt = 0; nt < 4; ++nt) {
      f32x4 zv = {0.0f, 0.0f, 0.0f, 0.0f};
      acc[mt][nt] = zv;
    }

#define STAGE_CHUNK(ks_, buf_)                                                  \
  {                                                                             \
    const float* g_ = zb + rloc * 512 + (ks_) * 32 + foff;                      \
    _Pragma("unroll")                                                           \
    for (int i_ = 0; i_ < 8; ++i_)                                              \
      __builtin_amdgcn_global_load_lds(                                         \
          (const __attribute__((address_space(1))) void*)(g_ + i_ * 8 * 512),   \
          (__attribute__((address_space(3))) void*)((buf_) + i_ * 1024),        \
          16, 0, 0);                                                            \
  }

#define LOADB(ks_)                                                              \
  {                                                                             \
    const u32x4* ph_ = wfh + (ks_) * 256 + lane;                                \
    _Pragma("unroll")                                                           \
    for (int nt_ = 0; nt_ < 4; ++nt_) {                                         \
      bh[nt_].u = ph_[nt_ * 64];                                                \
    }                                                                           \
  }

  FragU bh[4];

  // prologue (retirement order): stage(0)[8] < B(0)[4] < stage(1)[8]
  STAGE_CHUNK(0, stg);
  LOADB(0);
  STAGE_CHUNK(1, stg + 8192);

  const int swz = (r & 7) << 4;

#pragma unroll
  for (int ks = 0; ks < 16; ++ks) {
    unsigned char* cur = stg + (ks & 1) * 8192;

    // wait 1: drain stage(ks); B(ks)(4) + stage(ks+1)(8) stay in flight
    if (ks < 15) asm volatile("s_waitcnt vmcnt(12)" ::: "memory");
    else         asm volatile("s_waitcnt vmcnt(4)"  ::: "memory");
    __builtin_amdgcn_sched_barrier(0);

    // A-frags from LDS (swizzled ds_read_b128), convert to bf16 —
    // executes under B(ks)'s L2 latency. Row mt*16+r, swz = (r&7)<<4.
    FragU h[4];
#pragma unroll
    for (int mt = 0; mt < 4; ++mt) {
      const unsigned char* cm = cur + (mt * 16 + r) * 128;
      f32x4 a0 = *(const f32x4*)(cm + ((kg * 32) ^ swz));
      f32x4 a1 = *(const f32x4*)(cm + ((kg * 32 + 16) ^ swz));
#pragma unroll
      for (int j = 0; j < 4; ++j) {
        h[mt].v[j]     = (bf16_t)a0[j];
        h[mt].v[4 + j] = (bf16_t)a1[j];
      }
    }
    __builtin_amdgcn_sched_barrier(0);

    // wait 2: drain B(ks); stage(ks+1) stays in flight
    if (ks < 15) asm volatile("s_waitcnt vmcnt(8)" ::: "memory");
    else         asm volatile("s_waitcnt vmcnt(0)" ::: "memory");
    __builtin_amdgcn_sched_barrier(0);

#pragma unroll
    for (int nt = 0; nt < 4; ++nt)
#pragma unroll
      for (int mt = 0; mt < 4; ++mt)
        acc[mt][nt] = MFMA16(h[mt].v, bh[nt].v, acc[mt][nt]);
    __builtin_amdgcn_sched_barrier(0);

    // issue next-iter operands AFTER MFMAs consumed bh (no rename):
    // retirement order stays stage < B < stage.
    if (ks < 15) LOADB(ks + 1);
    if (ks < 14) STAGE_CHUNK(ks + 2, cur);  // cur's ds_reads retired above
  }
#undef STAGE_CHUNK
#undef LOADB

  // staging area is dead only after ALL waves finish their K-loop
  __syncthreads();

  float (*lds)[65] = (float(*)[65])smem;  // logits tile aliases staging

  // C layout: col = lane&15, row = (lane>>4)*4 + i  [m89-verified]
#pragma unroll
  for (int mt = 0; mt < 4; ++mt)
#pragma unroll
    for (int nt = 0; nt < 4; ++nt)
#pragma unroll
      for (int i = 0; i < 4; ++i)
        lds[wave * 64 + mt * 16 + kg * 4 + i][nt * 16 + r] = acc[mt][nt][i];

  __syncthreads();

  // Epilogue: one thread per row (256 rows), vectorized xq/out. Per group:
  // softmax(13) + rule mix.
  // rules = [a, b-2, b-1, b+1, b+2, a-b, a+b, min, max, b+2, b+1, b-2, b-1]
  {
    int row = tid;
    long long grow = brow + row;
    f32x4 xa = *(const f32x4*)(xq + grow * 8);      // a, groups 0..3
    f32x4 xb = *(const f32x4*)(xq + grow * 8 + 4);  // b, groups 0..3
    f32x4 res;
#pragma unroll
    for (int g = 0; g < 4; ++g) {
      float a  = xa[g];
      float bq = xb[g];
      float l[13];
      float m = -1e30f;
#pragma unroll
      for (int u = 0; u < 13; ++u) {
        l[u] = lds[row][g * 13 + u] + lds_bias[g * 13 + u];
        m = fmaxf(m, l[u]);
      }
      float s = 0.0f;
#pragma unroll
      for (int u = 0; u < 13; ++u) {
        float e = __expf(l[u] - m);
        l[u] = e;
        s += e;
      }
      float num = a * l[0]
                + (bq - 2.0f) * (l[1] + l[11])
                + (bq - 1.0f) * (l[2] + l[12])
                + (bq + 1.0f) * (l[3] + l[10])
                + (bq + 2.0f) * (l[4] + l[9])
                + (a - bq) * l[5]
                + (a + bq) * l[6]
                + fminf(a, bq) * l[7]
                + fmaxf(a, bq) * l[8];
      res[g] = num / s;
    }
    *(f32x4*)(out + grow * 4) = res;
  }
}

extern "C" void kernel_launch(void* const* d_in, const int* in_sizes, int n_in,
                              void* d_out, int out_size, void* d_ws, size_t ws_size,
                              hipStream_t stream) {
  const float* z    = (const float*)d_in[0];  // (B, 512)
  const float* xq   = (const float*)d_in[1];  // (B, 2, 4)
  const float* W    = (const float*)d_in[2];  // (512, 52)
  const float* bias = (const float*)d_in[3];  // (52,)
  float* out = (float*)d_out;                 // (B, 1, 4)

  const int B = in_sizes[0] / 512;            // 262144

  u32x4* wf = (u32x4*)d_ws;

  hipLaunchKernelGGL(pack_w_kernel, dim3(16), dim3(256), 0, stream, W, wf);

  const int blocks = B / 256;                 // 1024
  hipLaunchKernelGGL(raven_main_kernel, dim3(blocks), dim3(256), 0, stream,
                     z, xq, (const u32x4*)wf, bias, out);
}

// Round 13
// 108.445 us; speedup vs baseline: 1.0306x; 1.0306x over previous
//
#include <hip/hip_runtime.h>
#include <stdint.h>

typedef __bf16 bf16_t;
typedef bf16_t bf16x8 __attribute__((ext_vector_type(8)));
typedef float f32x4 __attribute__((ext_vector_type(4)));
typedef uint32_t u32x4 __attribute__((ext_vector_type(4)));
typedef uint16_t u16x8 __attribute__((ext_vector_type(8)));

union FragU { u32x4 u; bf16x8 v; u16x8 s; };

__device__ __forceinline__ uint16_t f2bf_rne(float f) {
  uint32_t u = __float_as_uint(f);
  return (uint16_t)((u + 0x7fffu + ((u >> 16) & 1u)) >> 16);
}

// ---------------------------------------------------------------------------
// Kernel 1: pack W (512x52 f32) into MFMA B-fragment layout, single bf16.
// B-frag for mfma_f32_16x16x32_bf16: lane l holds B[k][n], n = nt*16+(l&15),
// k = ks*32 + (l>>4)*8 + j. N padded 52->64. ws: wf[4096] u32x4 (64 KB).
// ---------------------------------------------------------------------------
__global__ __launch_bounds__(256) void pack_w_kernel(
    const float* __restrict__ W, u32x4* __restrict__ wf) {
  int idx = blockIdx.x * 256 + threadIdx.x;
  if (idx >= 4096) return;
  int lane = idx & 63;
  int nt   = (idx >> 6) & 3;
  int ks   = idx >> 8;
  int n  = nt * 16 + (lane & 15);
  int kb = ks * 32 + (lane >> 4) * 8;
  FragU hi;
#pragma unroll
  for (int j = 0; j < 8; ++j) {
    float w = (n < 52) ? W[(kb + j) * 52 + n] : 0.0f;
    hi.s[j] = f2bf_rne(w);
  }
  wf[idx] = hi.u;
}

#define MFMA16(a, b, c) __builtin_amdgcn_mfma_f32_16x16x32_bf16((a), (b), (c), 0, 0, 0)

// ---------------------------------------------------------------------------
// Kernel 2: fused GEMM + bias + softmax(13) + rule mix.
// r11 structure + B REGISTER DOUBLE-BUFFER -> ONE wait per iter.
// FIFO at iter top: [B(ks)4, stage(ks)4, B(ks+1)4, stage(ks+1)4];
// vmcnt(8) drains {B(ks), stage(ks)} together (B has >=1 iter of L2 slack).
// After MFMA: LOADB(ks+2) into the just-consumed bh[ks&1], STAGE(ks+2).
// LDS union: staging [4 waves][2][4096 B] = 32 KB  /  logits[128][65] f32.
// 4 blocks/CU, 16 waves/CU.
// ---------------------------------------------------------------------------
__global__ __launch_bounds__(256, 4) void raven_main_kernel(
    const float* __restrict__ z, const float* __restrict__ xq,
    const u32x4* __restrict__ wfh,
    const float* __restrict__ bias, float* __restrict__ out) {
  __shared__ __align__(16) unsigned char smem[33280];  // max(32768, 128*65*4)
  __shared__ float lds_bias[52];

  const int tid  = threadIdx.x;
  const int wave = tid >> 6;
  const int lane = tid & 63;
  const int r  = lane & 15;   // A row within 16-tile / C col
  const int kg = lane >> 4;   // k-group (8 contiguous k per lane)

  if (tid < 52) lds_bias[tid] = bias[tid];

  const long long brow = (long long)blockIdx.x * 128;
  const long long wrow = brow + (long long)wave * 32;
  const float* zb = z + wrow * 512;

  unsigned char* stg = smem + wave * 8192;  // [2][4096]

  // staging: lane covers bytes [(lane&7)*16,+16) of row (i*8 + (lane>>3));
  // source col pre-swizzled: foff = 4*((lane&7)^rloc)  (HW-verified r6)
  const int rloc = lane >> 3;
  const int foff = 4 * ((lane & 7) ^ rloc);

  f32x4 acc[2][4];
#pragma unroll
  for (int mt = 0; mt < 2; ++mt)
#pragma unroll
    for (int nt = 0; nt < 4; ++nt) {
      f32x4 zv = {0.0f, 0.0f, 0.0f, 0.0f};
      acc[mt][nt] = zv;
    }

#define STAGE_CHUNK(ks_, buf_)                                                  \
  {                                                                             \
    const float* g_ = zb + rloc * 512 + (ks_) * 32 + foff;                      \
    _Pragma("unroll")                                                           \
    for (int i_ = 0; i_ < 4; ++i_)                                              \
      __builtin_amdgcn_global_load_lds(                                         \
          (const __attribute__((address_space(1))) void*)(g_ + i_ * 8 * 512),   \
          (__attribute__((address_space(3))) void*)((buf_) + i_ * 1024),        \
          16, 0, 0);                                                            \
  }

#define LOADB(ks_, set_)                                                        \
  {                                                                             \
    const u32x4* ph_ = wfh + (ks_) * 256 + lane;                                \
    _Pragma("unroll")                                                           \
    for (int nt_ = 0; nt_ < 4; ++nt_) {                                         \
      bh[set_][nt_].u = ph_[nt_ * 64];                                          \
    }                                                                           \
  }

  FragU bh[2][4];

  // prologue FIFO: B(0) < stage(0) < B(1) < stage(1)
  LOADB(0, 0);
  STAGE_CHUNK(0, stg);
  LOADB(1, 1);
  STAGE_CHUNK(1, stg + 4096);

  const int swz = (r & 7) << 4;

#pragma unroll
  for (int ks = 0; ks < 16; ++ks) {
    unsigned char* cur = stg + (ks & 1) * 4096;

    // single wait: drain {B(ks), stage(ks)}; B(ks+1)+stage(ks+1) in flight
    if (ks < 15) asm volatile("s_waitcnt vmcnt(8)" ::: "memory");
    else         asm volatile("s_waitcnt vmcnt(0)" ::: "memory");
    __builtin_amdgcn_sched_barrier(0);

    // A-frags from LDS (swizzled ds_read_b128), convert to bf16
    const unsigned char* c0 = cur + r * 128;
    const unsigned char* c1 = cur + (r + 16) * 128;
    f32x4 a00 = *(const f32x4*)(c0 + ((kg * 32) ^ swz));
    f32x4 a01 = *(const f32x4*)(c0 + ((kg * 32 + 16) ^ swz));
    f32x4 a10 = *(const f32x4*)(c1 + ((kg * 32) ^ swz));
    f32x4 a11 = *(const f32x4*)(c1 + ((kg * 32 + 16) ^ swz));

    FragU h0, h1;
#pragma unroll
    for (int j = 0; j < 4; ++j) {
      h0.v[j]     = (bf16_t)a00[j];
      h0.v[4 + j] = (bf16_t)a01[j];
      h1.v[j]     = (bf16_t)a10[j];
      h1.v[4 + j] = (bf16_t)a11[j];
    }

    const int cs = ks & 1;
#pragma unroll
    for (int nt = 0; nt < 4; ++nt) {
      acc[0][nt] = MFMA16(h0.v, bh[cs][nt].v, acc[0][nt]);
      acc[1][nt] = MFMA16(h1.v, bh[cs][nt].v, acc[1][nt]);
    }
    __builtin_amdgcn_sched_barrier(0);

    // issue next operands AFTER MFMAs consumed bh[cs] (overwrite it):
    // FIFO gains B(ks+2) < stage(ks+2), preserving the single-wait math.
    if (ks < 14) {
      LOADB(ks + 2, cs);
      STAGE_CHUNK(ks + 2, cur);  // cur's ds_reads retired (lgkm in-order)
    }
  }
#undef STAGE_CHUNK
#undef LOADB

  // staging area is dead only after ALL waves finish their K-loop
  __syncthreads();

  float (*lds)[65] = (float(*)[65])smem;  // logits tile aliases staging

  // C layout: col = lane&15, row = (lane>>4)*4 + i  [m89-verified]
#pragma unroll
  for (int mt = 0; mt < 2; ++mt)
#pragma unroll
    for (int nt = 0; nt < 4; ++nt)
#pragma unroll
      for (int i = 0; i < 4; ++i)
        lds[wave * 32 + mt * 16 + kg * 4 + i][nt * 16 + r] = acc[mt][nt][i];

  __syncthreads();

  // Epilogue: one thread per row, vectorized xq/out. Per group: softmax(13)
  // + rule mix. rules = [a,b-2,b-1,b+1,b+2,a-b,a+b,min,max,b+2,b+1,b-2,b-1]
  if (tid < 128) {
    int row = tid;
    long long grow = brow + row;
    f32x4 xa = *(const f32x4*)(xq + grow * 8);      // a, groups 0..3
    f32x4 xb = *(const f32x4*)(xq + grow * 8 + 4);  // b, groups 0..3
    f32x4 res;
#pragma unroll
    for (int g = 0; g < 4; ++g) {
      float a  = xa[g];
      float bq = xb[g];
      float l[13];
      float m = -1e30f;
#pragma unroll
      for (int u = 0; u < 13; ++u) {
        l[u] = lds[row][g * 13 + u] + lds_bias[g * 13 + u];
        m = fmaxf(m, l[u]);
      }
      float s = 0.0f;
#pragma unroll
      for (int u = 0; u < 13; ++u) {
        float e = __expf(l[u] - m);
        l[u] = e;
        s += e;
      }
      float num = a * l[0]
                + (bq - 2.0f) * (l[1] + l[11])
                + (bq - 1.0f) * (l[2] + l[12])
                + (bq + 1.0f) * (l[3] + l[10])
                + (bq + 2.0f) * (l[4] + l[9])
                + (a - bq) * l[5]
                + (a + bq) * l[6]
                + fminf(a, bq) * l[7]
                + fmaxf(a, bq) * l[8];
      res[g] = num / s;
    }
    *(f32x4*)(out + grow * 4) = res;
  }
}

extern "C" void kernel_launch(void* const* d_in, const int* in_sizes, int n_in,
                              void* d_out, int out_size, void* d_ws, size_t ws_size,
                              hipStream_t stream) {
  const float* z    = (const float*)d_in[0];  // (B, 512)
  const float* xq   = (const float*)d_in[1];  // (B, 2, 4)
  const float* W    = (const float*)d_in[2];  // (512, 52)
  const float* bias = (const float*)d_in[3];  // (52,)
  float* out = (float*)d_out;                 // (B, 1, 4)

  const int B = in_sizes[0] / 512;            // 262144

  u32x4* wf = (u32x4*)d_ws;

  hipLaunchKernelGGL(pack_w_kernel, dim3(16), dim3(256), 0, stream, W, wf);

  const int blocks = B / 128;                 // 2048
  hipLaunchKernelGGL(raven_main_kernel, dim3(blocks), dim3(256), 0, stream,
                     z, xq, (const u32x4*)wf, bias, out);
}

// Round 14
// 108.148 us; speedup vs baseline: 1.0334x; 1.0027x over previous
//
#include <hip/hip_runtime.h>
#include <stdint.h>

typedef __bf16 bf16_t;
typedef bf16_t bf16x8 __attribute__((ext_vector_type(8)));
typedef float f32x2 __attribute__((ext_vector_type(2)));
typedef float f32x4 __attribute__((ext_vector_type(4)));
typedef uint32_t u32x4 __attribute__((ext_vector_type(4)));
typedef uint16_t u16x8 __attribute__((ext_vector_type(8)));

union FragU { u32x4 u; bf16x8 v; u16x8 s; };

__device__ __forceinline__ uint16_t f2bf_rne(float f) {
  uint32_t u = __float_as_uint(f);
  return (uint16_t)((u + 0x7fffu + ((u >> 16) & 1u)) >> 16);
}

// ---------------------------------------------------------------------------
// Kernel 1: pack W (512x52 f32) into MFMA B-fragment layout, single bf16.
// B-frag for mfma_f32_16x16x32_bf16: lane l holds B[k][n], n = nt*16+(l&15),
// k = ks*32 + (l>>4)*8 + j. N padded 52->64. ws: wf[4096] u32x4 (64 KB).
// ---------------------------------------------------------------------------
__global__ __launch_bounds__(256) void pack_w_kernel(
    const float* __restrict__ W, u32x4* __restrict__ wf) {
  int idx = blockIdx.x * 256 + threadIdx.x;
  if (idx >= 4096) return;
  int lane = idx & 63;
  int nt   = (idx >> 6) & 3;
  int ks   = idx >> 8;
  int n  = nt * 16 + (lane & 15);
  int kb = ks * 32 + (lane >> 4) * 8;
  FragU hi;
#pragma unroll
  for (int j = 0; j < 8; ++j) {
    float w = (n < 52) ? W[(kb + j) * 52 + n] : 0.0f;
    hi.s[j] = f2bf_rne(w);
  }
  wf[idx] = hi.u;
}

#define MFMA16(a, b, c) __builtin_amdgcn_mfma_f32_16x16x32_bf16((a), (b), (c), 0, 0, 0)

// ---------------------------------------------------------------------------
// Kernel 2: fused GEMM + bias + softmax(13) + rule mix.
// K-loop identical to r13 (best: 108.4 us): single vmcnt(8) wait, B register
// double-buffer, double-buffered global_load_lds staging.
// NEW: (1) logits stored TRANSPOSED lds_t[64][132] via ds_write_b128 (8 wide
// writes/thread instead of 32 scalar); (2) epilogue over ALL 256 threads
// (2 groups/thread, float2 out). LDS union: staging 32 KB / lds_t 33.8 KB.
// 4 blocks/CU, 16 waves/CU.
// ---------------------------------------------------------------------------
__global__ __launch_bounds__(256, 4) void raven_main_kernel(
    const float* __restrict__ z, const float* __restrict__ xq,
    const u32x4* __restrict__ wfh,
    const float* __restrict__ bias, float* __restrict__ out) {
  __shared__ __align__(16) unsigned char smem[33792];  // max(32768, 64*132*4)
  __shared__ float lds_bias[52];

  const int tid  = threadIdx.x;
  const int wave = tid >> 6;
  const int lane = tid & 63;
  const int r  = lane & 15;   // A row within 16-tile / C col
  const int kg = lane >> 4;   // k-group (8 contiguous k per lane)

  if (tid < 52) lds_bias[tid] = bias[tid];

  const long long brow = (long long)blockIdx.x * 128;
  const long long wrow = brow + (long long)wave * 32;
  const float* zb = z + wrow * 512;

  unsigned char* stg = smem + wave * 8192;  // [2][4096]

  // staging: lane covers bytes [(lane&7)*16,+16) of row (i*8 + (lane>>3));
  // source col pre-swizzled: foff = 4*((lane&7)^rloc)  (HW-verified r6)
  const int rloc = lane >> 3;
  const int foff = 4 * ((lane & 7) ^ rloc);

  f32x4 acc[2][4];
#pragma unroll
  for (int mt = 0; mt < 2; ++mt)
#pragma unroll
    for (int nt = 0; nt < 4; ++nt) {
      f32x4 zv = {0.0f, 0.0f, 0.0f, 0.0f};
      acc[mt][nt] = zv;
    }

#define STAGE_CHUNK(ks_, buf_)                                                  \
  {                                                                             \
    const float* g_ = zb + rloc * 512 + (ks_) * 32 + foff;                      \
    _Pragma("unroll")                                                           \
    for (int i_ = 0; i_ < 4; ++i_)                                              \
      __builtin_amdgcn_global_load_lds(                                         \
          (const __attribute__((address_space(1))) void*)(g_ + i_ * 8 * 512),   \
          (__attribute__((address_space(3))) void*)((buf_) + i_ * 1024),        \
          16, 0, 0);                                                            \
  }

#define LOADB(ks_, set_)                                                        \
  {                                                                             \
    const u32x4* ph_ = wfh + (ks_) * 256 + lane;                                \
    _Pragma("unroll")                                                           \
    for (int nt_ = 0; nt_ < 4; ++nt_) {                                         \
      bh[set_][nt_].u = ph_[nt_ * 64];                                          \
    }                                                                           \
  }

  FragU bh[2][4];

  // prologue FIFO: B(0) < stage(0) < B(1) < stage(1)
  LOADB(0, 0);
  STAGE_CHUNK(0, stg);
  LOADB(1, 1);
  STAGE_CHUNK(1, stg + 4096);

  const int swz = (r & 7) << 4;

#pragma unroll
  for (int ks = 0; ks < 16; ++ks) {
    unsigned char* cur = stg + (ks & 1) * 4096;

    // single wait: drain {B(ks), stage(ks)}; B(ks+1)+stage(ks+1) in flight
    if (ks < 15) asm volatile("s_waitcnt vmcnt(8)" ::: "memory");
    else         asm volatile("s_waitcnt vmcnt(0)" ::: "memory");
    __builtin_amdgcn_sched_barrier(0);

    // A-frags from LDS (swizzled ds_read_b128), convert to bf16
    const unsigned char* c0 = cur + r * 128;
    const unsigned char* c1 = cur + (r + 16) * 128;
    f32x4 a00 = *(const f32x4*)(c0 + ((kg * 32) ^ swz));
    f32x4 a01 = *(const f32x4*)(c0 + ((kg * 32 + 16) ^ swz));
    f32x4 a10 = *(const f32x4*)(c1 + ((kg * 32) ^ swz));
    f32x4 a11 = *(const f32x4*)(c1 + ((kg * 32 + 16) ^ swz));

    FragU h0, h1;
#pragma unroll
    for (int j = 0; j < 4; ++j) {
      h0.v[j]     = (bf16_t)a00[j];
      h0.v[4 + j] = (bf16_t)a01[j];
      h1.v[j]     = (bf16_t)a10[j];
      h1.v[4 + j] = (bf16_t)a11[j];
    }

    const int cs = ks & 1;
#pragma unroll
    for (int nt = 0; nt < 4; ++nt) {
      acc[0][nt] = MFMA16(h0.v, bh[cs][nt].v, acc[0][nt]);
      acc[1][nt] = MFMA16(h1.v, bh[cs][nt].v, acc[1][nt]);
    }
    __builtin_amdgcn_sched_barrier(0);

    // issue next operands AFTER MFMAs consumed bh[cs] (overwrite it):
    // FIFO gains B(ks+2) < stage(ks+2), preserving the single-wait math.
    if (ks < 14) {
      LOADB(ks + 2, cs);
      STAGE_CHUNK(ks + 2, cur);  // cur's ds_reads retired (lgkm in-order)
    }
  }
#undef STAGE_CHUNK
#undef LOADB

  // staging area is dead only after ALL waves finish their K-loop
  __syncthreads();

  // TRANSPOSED logits tile: lds_t[col][local_row], stride 132 (pad 4).
  // C layout: col = nt*16 + r, row = wave*32 + mt*16 + kg*4 + i — i is the
  // fast (consecutive-address) index -> one ds_write_b128 per (mt, nt).
  float (*lds_t)[132] = (float(*)[132])smem;
#pragma unroll
  for (int mt = 0; mt < 2; ++mt)
#pragma unroll
    for (int nt = 0; nt < 4; ++nt)
      *(f32x4*)&lds_t[nt * 16 + r][wave * 32 + mt * 16 + kg * 4] = acc[mt][nt];

  __syncthreads();

  // Epilogue over ALL 256 threads: thread t -> row = t>>1, groups
  // gp = (t&1)*2 .. gp+1. Per group: softmax(13) + rule mix.
  // rules = [a, b-2, b-1, b+1, b+2, a-b, a+b, min, max, b+2, b+1, b-2, b-1]
  {
    const int row = tid >> 1;
    const int gp  = (tid & 1) * 2;
    const long long grow = brow + row;
    f32x2 res;
#pragma unroll
    for (int gi = 0; gi < 2; ++gi) {
      const int g = gp + gi;
      float a  = xq[grow * 8 + g];
      float bq = xq[grow * 8 + 4 + g];
      float l[13];
      float m = -1e30f;
#pragma unroll
      for (int u = 0; u < 13; ++u) {
        l[u] = lds_t[g * 13 + u][row] + lds_bias[g * 13 + u];
        m = fmaxf(m, l[u]);
      }
      float s = 0.0f;
#pragma unroll
      for (int u = 0; u < 13; ++u) {
        float e = __expf(l[u] - m);
        l[u] = e;
        s += e;
      }
      float num = a * l[0]
                + (bq - 2.0f) * (l[1] + l[11])
                + (bq - 1.0f) * (l[2] + l[12])
                + (bq + 1.0f) * (l[3] + l[10])
                + (bq + 2.0f) * (l[4] + l[9])
                + (a - bq) * l[5]
                + (a + bq) * l[6]
                + fminf(a, bq) * l[7]
                + fmaxf(a, bq) * l[8];
      res[gi] = num / s;
    }
    *(f32x2*)(out + grow * 4 + gp) = res;
  }
}

extern "C" void kernel_launch(void* const* d_in, const int* in_sizes, int n_in,
                              void* d_out, int out_size, void* d_ws, size_t ws_size,
                              hipStream_t stream) {
  const float* z    = (const float*)d_in[0];  // (B, 512)
  const float* xq   = (const float*)d_in[1];  // (B, 2, 4)
  const float* W    = (const float*)d_in[2];  // (512, 52)
  const float* bias = (const float*)d_in[3];  // (52,)
  float* out = (float*)d_out;                 // (B, 1, 4)

  const int B = in_sizes[0] / 512;            // 262144

  u32x4* wf = (u32x4*)d_ws;

  hipLaunchKernelGGL(pack_w_kernel, dim3(16), dim3(256), 0, stream, W, wf);

  const int blocks = B / 128;                 // 2048
  hipLaunchKernelGGL(raven_main_kernel, dim3(blocks), dim3(256), 0, stream,
                     z, xq, (const u32x4*)wf, bias, out);
}

// Round 15
// 105.854 us; speedup vs baseline: 1.0558x; 1.0217x over previous
//
#include <hip/hip_runtime.h>
#include <stdint.h>

typedef __bf16 bf16_t;
typedef bf16_t bf16x8 __attribute__((ext_vector_type(8)));
typedef float f32x2 __attribute__((ext_vector_type(2)));
typedef float f32x4 __attribute__((ext_vector_type(4)));
typedef uint32_t u32x4 __attribute__((ext_vector_type(4)));
typedef uint16_t u16x8 __attribute__((ext_vector_type(8)));

union FragU { u32x4 u; bf16x8 v; u16x8 s; };

__device__ __forceinline__ uint16_t f2bf_rne(float f) {
  uint32_t u = __float_as_uint(f);
  return (uint16_t)((u + 0x7fffu + ((u >> 16) & 1u)) >> 16);
}

// ---------------------------------------------------------------------------
// Kernel 1: pack W (512x52 f32) into MFMA B-fragment layout, single bf16.
// B-frag for mfma_f32_16x16x32_bf16: lane l holds B[k][n], n = nt*16+(l&15),
// k = ks32*32 + (l>>4)*8 + j. N padded 52->64. ws: wf[4096] u32x4 (64 KB).
// ---------------------------------------------------------------------------
__global__ __launch_bounds__(256) void pack_w_kernel(
    const float* __restrict__ W, u32x4* __restrict__ wf) {
  int idx = blockIdx.x * 256 + threadIdx.x;
  if (idx >= 4096) return;
  int lane = idx & 63;
  int nt   = (idx >> 6) & 3;
  int ks   = idx >> 8;
  int n  = nt * 16 + (lane & 15);
  int kb = ks * 32 + (lane >> 4) * 8;
  FragU hi;
#pragma unroll
  for (int j = 0; j < 8; ++j) {
    float w = (n < 52) ? W[(kb + j) * 52 + n] : 0.0f;
    hi.s[j] = f2bf_rne(w);
  }
  wf[idx] = hi.u;
}

#define MFMA16(a, b, c) __builtin_amdgcn_mfma_f32_16x16x32_bf16((a), (b), (c), 0, 0, 0)

// ---------------------------------------------------------------------------
// Kernel 2: fused GEMM + bias + softmax(13) + rule mix — BK=64 GRANULE TEST.
// Staging instr covers 4 rows x 256 B contiguous runs (vs 128 B at BK=32):
// halves DRAM page-activates per byte (H7). Pipeline identical to r13:
// single-wait vmcnt(16), B register double-buffer, dbuf staging. 8 K-iters,
// per iter: 8 stage + 8 B + 16 MFMA. LDS: staging [4][2][8192]=64 KB union
// logits_t[64][132]. 2 blocks/CU, 8 waves/CU (same occupancy as r12 -> clean
// granule-only A/B vs r12's 111.8 us).
// ---------------------------------------------------------------------------
__global__ __launch_bounds__(256, 2) void raven_main_kernel(
    const float* __restrict__ z, const float* __restrict__ xq,
    const u32x4* __restrict__ wfh,
    const float* __restrict__ bias, float* __restrict__ out) {
  __shared__ __align__(16) unsigned char smem[65536];  // staging / logits_t union
  __shared__ float lds_bias[52];

  const int tid  = threadIdx.x;
  const int wave = tid >> 6;
  const int lane = tid & 63;
  const int r  = lane & 15;   // A row within 16-tile / C col
  const int kg = lane >> 4;   // k-group (8 contiguous k per lane)

  if (tid < 52) lds_bias[tid] = bias[tid];

  const long long brow = (long long)blockIdx.x * 128;
  const long long wrow = brow + (long long)wave * 32;
  const float* zb = z + wrow * 512;

  unsigned char* stg = smem + wave * 16384;  // [2][8192]

  // staging: instr i covers rows i*4 + (lane>>4), 16 lanes x 16 B = 256 B/row;
  // source slot pre-swizzled: s' = (lane&15) ^ (srow&7); read XORs the same.
  const int rloc4 = lane >> 4;   // 0..3: row within instr
  const int slot  = lane & 15;   // 16 B slot within the 256 B row-chunk

  f32x4 acc[2][4];
#pragma unroll
  for (int mt = 0; mt < 2; ++mt)
#pragma unroll
    for (int nt = 0; nt < 4; ++nt) {
      f32x4 zv = {0.0f, 0.0f, 0.0f, 0.0f};
      acc[mt][nt] = zv;
    }

#define STAGE_CHUNK(ks_, buf_)                                                  \
  {                                                                             \
    _Pragma("unroll")                                                           \
    for (int i_ = 0; i_ < 8; ++i_) {                                            \
      const int srow_ = i_ * 4 + rloc4;                                         \
      const int foff_ = 4 * (slot ^ (srow_ & 7));                               \
      const float* g_ = zb + srow_ * 512 + (ks_) * 64 + foff_;                  \
      __builtin_amdgcn_global_load_lds(                                         \
          (const __attribute__((address_space(1))) void*)g_,                    \
          (__attribute__((address_space(3))) void*)((buf_) + i_ * 1024),        \
          16, 0, 0);                                                            \
    }                                                                           \
  }

#define LOADB(ks_, set_)                                                        \
  {                                                                             \
    const u32x4* p0_ = wfh + (2 * (ks_)) * 256 + lane;                          \
    const u32x4* p1_ = wfh + (2 * (ks_) + 1) * 256 + lane;                      \
    _Pragma("unroll")                                                           \
    for (int nt_ = 0; nt_ < 4; ++nt_) {                                         \
      bh[set_][nt_].u     = p0_[nt_ * 64];                                      \
      bh[set_][4 + nt_].u = p1_[nt_ * 64];                                      \
    }                                                                           \
  }

  FragU bh[2][8];

  // prologue FIFO: B(0)[8] < stage(0)[8] < B(1)[8] < stage(1)[8]
  LOADB(0, 0);
  STAGE_CHUNK(0, stg);
  LOADB(1, 1);
  STAGE_CHUNK(1, stg + 8192);

  const int swz = (r & 7) << 4;

#pragma unroll
  for (int ks = 0; ks < 8; ++ks) {
    unsigned char* cur = stg + (ks & 1) * 8192;

    // single wait: drain {B(ks), stage(ks)}; B(ks+1)+stage(ks+1) in flight
    if (ks < 7) asm volatile("s_waitcnt vmcnt(16)" ::: "memory");
    else        asm volatile("s_waitcnt vmcnt(0)"  ::: "memory");
    __builtin_amdgcn_sched_barrier(0);

    // A-frags from LDS: row stride 256 B, col = c*128 + kg*32 (+16), XOR swz
    FragU h[2][2];  // [c][mt]
#pragma unroll
    for (int c = 0; c < 2; ++c)
#pragma unroll
      for (int mt = 0; mt < 2; ++mt) {
        const unsigned char* cm = cur + (mt * 16 + r) * 256;
        f32x4 a0 = *(const f32x4*)(cm + ((c * 128 + kg * 32) ^ swz));
        f32x4 a1 = *(const f32x4*)(cm + ((c * 128 + kg * 32 + 16) ^ swz));
#pragma unroll
        for (int j = 0; j < 4; ++j) {
          h[c][mt].v[j]     = (bf16_t)a0[j];
          h[c][mt].v[4 + j] = (bf16_t)a1[j];
        }
      }

    const int cs = ks & 1;
#pragma unroll
    for (int c = 0; c < 2; ++c)
#pragma unroll
      for (int nt = 0; nt < 4; ++nt) {
        acc[0][nt] = MFMA16(h[c][0].v, bh[cs][c * 4 + nt].v, acc[0][nt]);
        acc[1][nt] = MFMA16(h[c][1].v, bh[cs][c * 4 + nt].v, acc[1][nt]);
      }
    __builtin_amdgcn_sched_barrier(0);

    // issue next operands AFTER MFMAs consumed bh[cs] (overwrite it):
    // FIFO gains B(ks+2)[8] < stage(ks+2)[8], preserving the wait math.
    if (ks < 6) {
      LOADB(ks + 2, cs);
      STAGE_CHUNK(ks + 2, cur);  // cur's ds_reads retired (lgkm in-order)
    }
  }
#undef STAGE_CHUNK
#undef LOADB

  // staging area is dead only after ALL waves finish their K-loop
  __syncthreads();

  // TRANSPOSED logits tile: lds_t[col][local_row], stride 132 (pad 4).
  // C layout: col = nt*16 + r, row = wave*32 + mt*16 + kg*4 + i.
  float (*lds_t)[132] = (float(*)[132])smem;
#pragma unroll
  for (int mt = 0; mt < 2; ++mt)
#pragma unroll
    for (int nt = 0; nt < 4; ++nt)
      *(f32x4*)&lds_t[nt * 16 + r][wave * 32 + mt * 16 + kg * 4] = acc[mt][nt];

  __syncthreads();

  // Epilogue over ALL 256 threads: thread t -> row = t>>1, groups
  // gp = (t&1)*2 .. gp+1. Per group: softmax(13) + rule mix.
  // rules = [a, b-2, b-1, b+1, b+2, a-b, a+b, min, max, b+2, b+1, b-2, b-1]
  {
    const int row = tid >> 1;
    const int gp  = (tid & 1) * 2;
    const long long grow = brow + row;
    f32x2 res;
#pragma unroll
    for (int gi = 0; gi < 2; ++gi) {
      const int g = gp + gi;
      float a  = xq[grow * 8 + g];
      float bq = xq[grow * 8 + 4 + g];
      float l[13];
      float m = -1e30f;
#pragma unroll
      for (int u = 0; u < 13; ++u) {
        l[u] = lds_t[g * 13 + u][row] + lds_bias[g * 13 + u];
        m = fmaxf(m, l[u]);
      }
      float s = 0.0f;
#pragma unroll
      for (int u = 0; u < 13; ++u) {
        float e = __expf(l[u] - m);
        l[u] = e;
        s += e;
      }
      float num = a * l[0]
                + (bq - 2.0f) * (l[1] + l[11])
                + (bq - 1.0f) * (l[2] + l[12])
                + (bq + 1.0f) * (l[3] + l[10])
                + (bq + 2.0f) * (l[4] + l[9])
                + (a - bq) * l[5]
                + (a + bq) * l[6]
                + fminf(a, bq) * l[7]
                + fmaxf(a, bq) * l[8];
      res[gi] = num / s;
    }
    *(f32x2*)(out + grow * 4 + gp) = res;
  }
}

extern "C" void kernel_launch(void* const* d_in, const int* in_sizes, int n_in,
                              void* d_out, int out_size, void* d_ws, size_t ws_size,
                              hipStream_t stream) {
  const float* z    = (const float*)d_in[0];  // (B, 512)
  const float* xq   = (const float*)d_in[1];  // (B, 2, 4)
  const float* W    = (const float*)d_in[2];  // (512, 52)
  const float* bias = (const float*)d_in[3];  // (52,)
  float* out = (float*)d_out;                 // (B, 1, 4)

  const int B = in_sizes[0] / 512;            // 262144

  u32x4* wf = (u32x4*)d_ws;

  hipLaunchKernelGGL(pack_w_kernel, dim3(16), dim3(256), 0, stream, W, wf);

  const int blocks = B / 128;                 // 2048
  hipLaunchKernelGGL(raven_main_kernel, dim3(blocks), dim3(256), 0, stream,
                     z, xq, (const u32x4*)wf, bias, out);
}